// Round 1
// 239.828 us; speedup vs baseline: 1.0230x; 1.0230x over previous
//
#include <hip/hip_runtime.h>
#include <hip/hip_bf16.h>

typedef __hip_bfloat16 bf16;
typedef unsigned int u32;
typedef unsigned short u16;

constexpr int N   = 50000;
constexpr int E   = 1600000;
constexpr int C   = 128;             // channels (H * 32)
constexpr int H   = 4;               // heads
constexpr int NB  = 782;             // dst buckets of 64 nodes (782*64 >= 50000)
constexpr int CAP = 2560;            // pairs capacity per bucket (mean 2048, +11 sigma)
constexpr int CHUNK = 4096;          // edges per kbin block
constexpr float NEG  = 0.2f;
constexpr float SEPS = 1e-16f;
constexpr float LEPS = 1e-5f;

__device__ __forceinline__ float lo16(u32 v) { return __uint_as_float(v << 16); }
__device__ __forceinline__ float hi16(u32 v) { return __uint_as_float(v & 0xFFFF0000u); }

// K1: h = x @ W, 16 nodes per block. x tile in LDS; W from global (L1/L2-hot).
// h stored bf16. Fused attention dots a_s, a_d.
__global__ __launch_bounds__(256) void k1_gemm(
    const float* __restrict__ x, const float* __restrict__ W,
    const float* __restrict__ att_s, const float* __restrict__ att_d,
    bf16* __restrict__ hb, float* __restrict__ as_, float* __restrict__ ad_)
{
    const int nb = blockIdx.x * 16;
    const int t  = threadIdx.x;
    __shared__ float sx[16 * 128];
    const float4* xg = (const float4*)(x + nb * 128);
    ((float4*)sx)[t]       = xg[t];
    ((float4*)sx)[t + 256] = xg[t + 256];
    __syncthreads();

    const int c = t & 127;           // output channel
    const int g = t >> 7;            // node group (0/1) of 8 nodes
    const float* xb = sx + (g << 10);
    float acc[8] = {0.f, 0.f, 0.f, 0.f, 0.f, 0.f, 0.f, 0.f};

    for (int k = 0; k < 128; k += 4) {
        const float w0 = W[(k + 0) * 128 + c];
        const float w1 = W[(k + 1) * 128 + c];
        const float w2 = W[(k + 2) * 128 + c];
        const float w3 = W[(k + 3) * 128 + c];
#pragma unroll
        for (int j = 0; j < 8; ++j) {
            const float4 xv = *(const float4*)(xb + j * 128 + k);
            acc[j] = fmaf(xv.x, w0, fmaf(xv.y, w1, fmaf(xv.z, w2, fmaf(xv.w, w3, acc[j]))));
        }
    }

    const int lane = t & 63;
    const int head = c >> 5;
    const float asc = att_s[c], adc = att_d[c];
#pragma unroll
    for (int j = 0; j < 8; ++j) {
        const int node = nb + (g << 3) + j;
        hb[node * 128 + c] = __float2bfloat16(acc[j]);
        float vs = acc[j] * asc;
        float vd = acc[j] * adc;
#pragma unroll
        for (int off = 16; off; off >>= 1) {
            vs += __shfl_xor(vs, off, 64);
            vd += __shfl_xor(vd, off, 64);
        }
        if ((lane & 31) == 0) {
            as_[node * H + head] = vs;
            ad_[node * H + head] = vd;
        }
    }
}

// KBIN: bin edges into NB dst-buckets as packed u32 (src | (dst&63)<<16).
// Two-phase per chunk: LDS int count -> global reserve -> scatter.
// Bucket runs are temporally clustered -> L2 merges write lines.
__global__ __launch_bounds__(256) void kbin(
    const int* __restrict__ ei, u32* __restrict__ gcur, u32* __restrict__ pairs)
{
    __shared__ u32 lcnt[NB], lbase[NB], lfill[NB];
    const int t = threadIdx.x;
    const int base = blockIdx.x * CHUNK;
    const int nE = min(CHUNK, E - base);
    for (int i = t; i < NB; i += 256) lcnt[i] = 0;
    __syncthreads();
    for (int i = t; i < nE; i += 256)
        atomicAdd(&lcnt[((u32)ei[E + base + i]) >> 6], 1u);
    __syncthreads();
    for (int i = t; i < NB; i += 256) {
        u32 cb = lcnt[i];
        lbase[i] = cb ? atomicAdd(&gcur[i], cb) : 0u;
        lfill[i] = 0u;
    }
    __syncthreads();
    for (int i = t; i < nE; i += 256) {
        u32 src = (u32)ei[base + i];
        u32 dst = (u32)ei[E + base + i];
        u32 b = dst >> 6;
        u32 pos = atomicAdd(&lfill[b], 1u);
        pairs[(size_t)b * CAP + lbase[b] + pos] = src | ((dst & 63u) << 16);
    }
}

// KSCAN: one wave — exclusive scan of gcur[NB] -> bbase; row_ptr[N] = E.
__global__ __launch_bounds__(64) void kscan(
    const u32* __restrict__ gcur, u32* __restrict__ bbase, int* __restrict__ row_ptr)
{
    const int t = threadIdx.x;
    u32 vals[13];
    u32 s = 0;
#pragma unroll
    for (int i = 0; i < 13; ++i) {
        int idx = t * 13 + i;
        u32 v = (idx < NB) ? gcur[idx] : 0u;
        vals[i] = s; s += v;
    }
    u32 incl = s;
#pragma unroll
    for (int off = 1; off < 64; off <<= 1) {
        u32 u = __shfl_up(incl, off, 64);
        if (t >= off) incl += u;
    }
    const u32 excl = incl - s;
#pragma unroll
    for (int i = 0; i < 13; ++i) {
        int idx = t * 13 + i;
        if (idx < NB) bbase[idx] = excl + vals[i];
    }
    if (t == 0) row_ptr[N] = E;
}

// KFILL2: block per bucket. Count per node (int LDS atomics), wave scan,
// write row_ptr and scatter u16 col within the bucket's narrow region.
__global__ __launch_bounds__(256) void kfill2(
    const u32* __restrict__ pairs, const u32* __restrict__ gcur,
    const u32* __restrict__ bbase, int* __restrict__ row_ptr, u16* __restrict__ col)
{
    __shared__ int jcnt[64], joff[64], jcur[64];
    const int b = blockIdx.x, t = threadIdx.x;
    const int cntb = (int)gcur[b];
    const int base = (int)bbase[b];
    if (t < 64) jcnt[t] = 0;
    __syncthreads();
    const u32* pr = pairs + (size_t)b * CAP;
    for (int i = t; i < cntb; i += 256) atomicAdd(&jcnt[pr[i] >> 16], 1);
    __syncthreads();
    if (t < 64) {
        int v = jcnt[t], incl = v;
#pragma unroll
        for (int off = 1; off < 64; off <<= 1) {
            int u = __shfl_up(incl, off, 64);
            if (t >= off) incl += u;
        }
        joff[t] = incl - v;
        const int n = b * 64 + t;
        if (n < N) row_ptr[n] = base + joff[t];
        jcur[t] = 0;
    }
    __syncthreads();
    for (int i = t; i < cntb; i += 256) {
        const u32 p = pr[i];
        const int j = p >> 16;
        const int pos = atomicAdd(&jcur[j], 1);
        col[base + joff[j] + pos] = (u16)(p & 0xFFFFu);
    }
}

// KD v2: fused attention-softmax aggregation + bias + LayerNorm + ELU.
// One wave per node. 16-edge tiles:
//   weight phase: lane (h*16+e) computes w[e][h] ONCE (was 16x redundant),
//                 per-lane den partials (tree-reduced at the end).
//   w broadcast via per-wave LDS row (ds_read_b128, 2-way bank alias = free).
//   readfirstlane(n) -> row_ptr via s_load; readlane(col) -> SGPR src node
//   -> hb row gather becomes saddr global_load with constant voffset (lane*4),
//   moving all gather address math to the SALU pipe.
__global__ __launch_bounds__(256) void kd_agg_ln(
    const int* __restrict__ row_ptr, const u16* __restrict__ col,
    const u32* __restrict__ hb, const float* __restrict__ as_,
    const float* __restrict__ ad_,
    const float* __restrict__ bias, const float* __restrict__ gamma,
    const float* __restrict__ beta, float* __restrict__ out)
{
    __shared__ float wlds[4][64];
    const int tid  = threadIdx.x;
    const int lane = tid & 63;
    const int wv   = __builtin_amdgcn_readfirstlane(tid >> 6);
    const int n    = __builtin_amdgcn_readfirstlane((int)blockIdx.x * 4 + (tid >> 6));
    if (n >= N) return;

    const int head  = lane >> 4;   // weight phase: head; accumulation: (lane*2)>>5 == same
    const int eoff  = lane & 15;   // weight phase: edge slot within tile
    const int wbase = head << 4;
    float* __restrict__ wrow = wlds[wv];

    const float adn = ad_[n * H + head];
    const float asn = as_[n * H + head];

    // self-loop (src == dst == n); every lane holds w_self for its own head
    float ls = asn + adn;
    ls = fmaxf(ls, NEG * ls);
    const float wself = __expf(ls);
    float den = (eoff == 0) ? wself : 0.f;   // count self-loop once per head group
    const u32 hvs = hb[n * 64 + lane];
    float num0 = wself * lo16(hvs);
    float num1 = wself * hi16(hvs);

    const int k0  = row_ptr[n];
    const int end = row_ptr[n + 1];

    for (int k = k0; k < end; k += 16) {
        const int cnt = min(16, end - k);
        int   colv = 0;
        float w    = 0.f;
        if (eoff < cnt) {
            colv = col[k + eoff];                    // 16 distinct u16, 4-way bcast
            const float a = as_[colv * H + head];    // 1 gather inst for 16 edges x 4 heads
            float le = a + adn;
            le = fmaxf(le, NEG * le);
            w = __expf(le);
        }
        den += w;
        wrow[lane] = w;                              // wave-private row: no __syncthreads

        int e = 0;
        for (; e + 4 <= cnt; e += 4) {
            const float4 w4 = *(const float4*)(wrow + wbase + e);
            const int s0 = __builtin_amdgcn_readlane(colv, e + 0);
            const int s1 = __builtin_amdgcn_readlane(colv, e + 1);
            const int s2 = __builtin_amdgcn_readlane(colv, e + 2);
            const int s3 = __builtin_amdgcn_readlane(colv, e + 3);
            const u32 v0 = hb[s0 * 64 + lane];       // saddr loads, shared voffset
            const u32 v1 = hb[s1 * 64 + lane];
            const u32 v2 = hb[s2 * 64 + lane];
            const u32 v3 = hb[s3 * 64 + lane];
            num0 = fmaf(w4.x, lo16(v0), num0); num1 = fmaf(w4.x, hi16(v0), num1);
            num0 = fmaf(w4.y, lo16(v1), num0); num1 = fmaf(w4.y, hi16(v1), num1);
            num0 = fmaf(w4.z, lo16(v2), num0); num1 = fmaf(w4.z, hi16(v2), num1);
            num0 = fmaf(w4.w, lo16(v3), num0); num1 = fmaf(w4.w, hi16(v3), num1);
        }
        for (; e < cnt; ++e) {
            const float we = wrow[wbase + e];
            const int  s  = __builtin_amdgcn_readlane(colv, e);
            const u32  v  = hb[s * 64 + lane];
            num0 = fmaf(we, lo16(v), num0);
            num1 = fmaf(we, hi16(v), num1);
        }
    }

    // reduce den partials across the 16 lanes of each head group
#pragma unroll
    for (int off = 1; off < 16; off <<= 1) den += __shfl_xor(den, off, 64);

    const int c0 = lane * 2;
    const float inv_den = 1.f / (den + SEPS);
    const float2 bi = *(const float2*)(bias + c0);
    float v0 = num0 * inv_den + bi.x;
    float v1 = num1 * inv_den + bi.y;

    float sum = v0 + v1;
#pragma unroll
    for (int off = 32; off; off >>= 1) sum += __shfl_xor(sum, off, 64);
    const float mu = sum * (1.0f / C);
    const float d0 = v0 - mu, d1 = v1 - mu;
    float sq = d0 * d0 + d1 * d1;
#pragma unroll
    for (int off = 32; off; off >>= 1) sq += __shfl_xor(sq, off, 64);
    const float inv = rsqrtf(sq * (1.0f / C) + LEPS);
    const float2 ga = *(const float2*)(gamma + c0);
    const float2 be = *(const float2*)(beta  + c0);
    float y0 = d0 * inv * ga.x + be.x;
    float y1 = d1 * inv * ga.y + be.y;
    y0 = y0 > 0.f ? y0 : __expf(y0) - 1.f;
    y1 = y1 > 0.f ? y1 : __expf(y1) - 1.f;
    float2 o; o.x = y0; o.y = y1;
    *(float2*)(out + (size_t)n * C + c0) = o;
}

extern "C" void kernel_launch(void* const* d_in, const int* in_sizes, int n_in,
                              void* d_out, int out_size, void* d_ws, size_t ws_size,
                              hipStream_t stream)
{
    const float* x     = (const float*)d_in[0];
    const int*   ei    = (const int*)  d_in[1];
    const float* W     = (const float*)d_in[2];
    const float* att_s = (const float*)d_in[3];
    const float* att_d = (const float*)d_in[4];
    const float* bias  = (const float*)d_in[5];
    const float* gamma = (const float*)d_in[6];
    const float* beta  = (const float*)d_in[7];
    float* out = (float*)d_out;

    // ws (~26 MB): hb bf16[N*C] | as_ | ad_ | pairs u32[NB*CAP] | col u16[E]
    //            | row_ptr int[N+1] | gcur u32[NB] | bbase u32[NB]
    char* p = (char*)d_ws;
    bf16*  hb      = (bf16*)p;   p += (size_t)N * C * sizeof(bf16);
    float* as_     = (float*)p;  p += (size_t)N * H * sizeof(float);
    float* ad_     = (float*)p;  p += (size_t)N * H * sizeof(float);
    u32*   pairs   = (u32*)p;    p += (size_t)NB * CAP * sizeof(u32);
    u16*   col     = (u16*)p;    p += ((size_t)E * sizeof(u16) + 15) & ~(size_t)15;
    int*   row_ptr = (int*)p;    p += ((size_t)(N + 1) * sizeof(int) + 15) & ~(size_t)15;
    u32*   gcur    = (u32*)p;    p += (size_t)NB * sizeof(u32);
    u32*   bbase   = (u32*)p;

    hipMemsetAsync(gcur, 0, NB * sizeof(u32), stream);
    k1_gemm<<<N / 16, 256, 0, stream>>>(x, W, att_s, att_d, hb, as_, ad_);
    kbin<<<(E + CHUNK - 1) / CHUNK, 256, 0, stream>>>(ei, gcur, pairs);
    kscan<<<1, 64, 0, stream>>>(gcur, bbase, row_ptr);
    kfill2<<<NB, 256, 0, stream>>>(pairs, gcur, bbase, row_ptr, col);
    kd_agg_ln<<<(N * 64) / 256, 256, 0, stream>>>(
        row_ptr, col, (const u32*)hb, as_, ad_, bias, gamma, beta, out);
}

// Round 2
// 238.951 us; speedup vs baseline: 1.0267x; 1.0037x over previous
//
#include <hip/hip_runtime.h>
#include <hip/hip_bf16.h>

typedef __hip_bfloat16 bf16;
typedef unsigned int u32;
typedef unsigned short u16;

constexpr int N   = 50000;
constexpr int E   = 1600000;
constexpr int C   = 128;             // channels (H * 32)
constexpr int H   = 4;               // heads
constexpr int NB  = 782;             // dst buckets of 64 nodes (782*64 >= 50000)
constexpr int CAP = 2560;            // pairs capacity per bucket (mean 2048, +11 sigma)
constexpr int CHUNK = 4096;          // edges per kbin block
constexpr float NEG  = 0.2f;
constexpr float SEPS = 1e-16f;
constexpr float LEPS = 1e-5f;

__device__ __forceinline__ float lo16(u32 v) { return __uint_as_float(v << 16); }
__device__ __forceinline__ float hi16(u32 v) { return __uint_as_float(v & 0xFFFF0000u); }

// K1: h = x @ W, 16 nodes per block. x tile in LDS; W from global (L1/L2-hot).
// h stored bf16. Fused attention dots a_s, a_d.
__global__ __launch_bounds__(256) void k1_gemm(
    const float* __restrict__ x, const float* __restrict__ W,
    const float* __restrict__ att_s, const float* __restrict__ att_d,
    bf16* __restrict__ hb, float* __restrict__ as_, float* __restrict__ ad_)
{
    const int nb = blockIdx.x * 16;
    const int t  = threadIdx.x;
    __shared__ float sx[16 * 128];
    const float4* xg = (const float4*)(x + nb * 128);
    ((float4*)sx)[t]       = xg[t];
    ((float4*)sx)[t + 256] = xg[t + 256];
    __syncthreads();

    const int c = t & 127;           // output channel
    const int g = t >> 7;            // node group (0/1) of 8 nodes
    const float* xb = sx + (g << 10);
    float acc[8] = {0.f, 0.f, 0.f, 0.f, 0.f, 0.f, 0.f, 0.f};

    for (int k = 0; k < 128; k += 4) {
        const float w0 = W[(k + 0) * 128 + c];
        const float w1 = W[(k + 1) * 128 + c];
        const float w2 = W[(k + 2) * 128 + c];
        const float w3 = W[(k + 3) * 128 + c];
#pragma unroll
        for (int j = 0; j < 8; ++j) {
            const float4 xv = *(const float4*)(xb + j * 128 + k);
            acc[j] = fmaf(xv.x, w0, fmaf(xv.y, w1, fmaf(xv.z, w2, fmaf(xv.w, w3, acc[j]))));
        }
    }

    const int lane = t & 63;
    const int head = c >> 5;
    const float asc = att_s[c], adc = att_d[c];
#pragma unroll
    for (int j = 0; j < 8; ++j) {
        const int node = nb + (g << 3) + j;
        hb[node * 128 + c] = __float2bfloat16(acc[j]);
        float vs = acc[j] * asc;
        float vd = acc[j] * adc;
#pragma unroll
        for (int off = 16; off; off >>= 1) {
            vs += __shfl_xor(vs, off, 64);
            vd += __shfl_xor(vd, off, 64);
        }
        if ((lane & 31) == 0) {
            as_[node * H + head] = vs;
            ad_[node * H + head] = vd;
        }
    }
}

// KBIN: bin edges into NB dst-buckets as packed u32 (src | (dst&63)<<16).
// Two-phase per chunk: LDS int count -> global reserve -> scatter.
// Bucket runs are temporally clustered -> L2 merges write lines.
__global__ __launch_bounds__(256) void kbin(
    const int* __restrict__ ei, u32* __restrict__ gcur, u32* __restrict__ pairs)
{
    __shared__ u32 lcnt[NB], lbase[NB], lfill[NB];
    const int t = threadIdx.x;
    const int base = blockIdx.x * CHUNK;
    const int nE = min(CHUNK, E - base);
    for (int i = t; i < NB; i += 256) lcnt[i] = 0;
    __syncthreads();
    for (int i = t; i < nE; i += 256)
        atomicAdd(&lcnt[((u32)ei[E + base + i]) >> 6], 1u);
    __syncthreads();
    for (int i = t; i < NB; i += 256) {
        u32 cb = lcnt[i];
        lbase[i] = cb ? atomicAdd(&gcur[i], cb) : 0u;
        lfill[i] = 0u;
    }
    __syncthreads();
    for (int i = t; i < nE; i += 256) {
        u32 src = (u32)ei[base + i];
        u32 dst = (u32)ei[E + base + i];
        u32 b = dst >> 6;
        u32 pos = atomicAdd(&lfill[b], 1u);
        pairs[(size_t)b * CAP + lbase[b] + pos] = src | ((dst & 63u) << 16);
    }
}

// KSCAN: one wave — exclusive scan of gcur[NB] -> bbase; row_ptr[N] = E.
__global__ __launch_bounds__(64) void kscan(
    const u32* __restrict__ gcur, u32* __restrict__ bbase, int* __restrict__ row_ptr)
{
    const int t = threadIdx.x;
    u32 vals[13];
    u32 s = 0;
#pragma unroll
    for (int i = 0; i < 13; ++i) {
        int idx = t * 13 + i;
        u32 v = (idx < NB) ? gcur[idx] : 0u;
        vals[i] = s; s += v;
    }
    u32 incl = s;
#pragma unroll
    for (int off = 1; off < 64; off <<= 1) {
        u32 u = __shfl_up(incl, off, 64);
        if (t >= off) incl += u;
    }
    const u32 excl = incl - s;
#pragma unroll
    for (int i = 0; i < 13; ++i) {
        int idx = t * 13 + i;
        if (idx < NB) bbase[idx] = excl + vals[i];
    }
    if (t == 0) row_ptr[N] = E;
}

// KFILL2: block per bucket. Count per node (int LDS atomics), wave scan,
// write row_ptr and scatter u16 col within the bucket's narrow region.
__global__ __launch_bounds__(256) void kfill2(
    const u32* __restrict__ pairs, const u32* __restrict__ gcur,
    const u32* __restrict__ bbase, int* __restrict__ row_ptr, u16* __restrict__ col)
{
    __shared__ int jcnt[64], joff[64], jcur[64];
    const int b = blockIdx.x, t = threadIdx.x;
    const int cntb = (int)gcur[b];
    const int base = (int)bbase[b];
    if (t < 64) jcnt[t] = 0;
    __syncthreads();
    const u32* pr = pairs + (size_t)b * CAP;
    for (int i = t; i < cntb; i += 256) atomicAdd(&jcnt[pr[i] >> 16], 1);
    __syncthreads();
    if (t < 64) {
        int v = jcnt[t], incl = v;
#pragma unroll
        for (int off = 1; off < 64; off <<= 1) {
            int u = __shfl_up(incl, off, 64);
            if (t >= off) incl += u;
        }
        joff[t] = incl - v;
        const int n = b * 64 + t;
        if (n < N) row_ptr[n] = base + joff[t];
        jcur[t] = 0;
    }
    __syncthreads();
    for (int i = t; i < cntb; i += 256) {
        const u32 p = pr[i];
        const int j = p >> 16;
        const int pos = atomicAdd(&jcur[j], 1);
        col[base + joff[j] + pos] = (u16)(p & 0xFFFFu);
    }
}

// KD v3: fused attention-softmax aggregation + bias + LayerNorm + ELU.
// One wave per node. 16-edge tiles, deep software pipeline:
//   - 16 hb gather loads in flight per tile (register array, full unroll)
//   - next tile's col + as_ gather prefetched during current tile's FMA phase
//   - weight phase cooperative: lane (h*16+e) computes w[e][h] once;
//     broadcast via per-wave LDS row (ds_read_b128, wave-private, no barrier)
//   - readfirstlane(n) -> scalar row_ptr; readlane(col) -> SGPR src node ->
//     saddr gather with shared voffset (lane*4): address math on SALU pipe.
__global__ __launch_bounds__(256) void kd_agg_ln(
    const int* __restrict__ row_ptr, const u16* __restrict__ col,
    const u32* __restrict__ hb, const float* __restrict__ as_,
    const float* __restrict__ ad_,
    const float* __restrict__ bias, const float* __restrict__ gamma,
    const float* __restrict__ beta, float* __restrict__ out)
{
    __shared__ float wlds[4][64];
    const int tid  = threadIdx.x;
    const int lane = tid & 63;
    const int wv   = __builtin_amdgcn_readfirstlane(tid >> 6);
    const int n    = __builtin_amdgcn_readfirstlane((int)blockIdx.x * 4 + (tid >> 6));
    if (n >= N) return;

    const int head  = lane >> 4;   // weight phase: head; accumulation: (lane*2)>>5 == same
    const int eoff  = lane & 15;   // weight phase: edge slot within tile
    const int wbase = head << 4;
    float* __restrict__ wrow = wlds[wv];

    const float adn = ad_[n * H + head];
    const float asn = as_[n * H + head];

    // self-loop (src == dst == n); every lane holds w_self for its own head
    float ls = asn + adn;
    ls = fmaxf(ls, NEG * ls);
    const float wself = __expf(ls);
    float den = (eoff == 0) ? wself : 0.f;   // count self-loop once per head group
    const u32 hvs = hb[n * 64 + lane];
    float num0 = wself * lo16(hvs);
    float num1 = wself * hi16(hvs);

    const int k0  = row_ptr[n];
    const int end = row_ptr[n + 1];
    const int deg   = end - k0;
    const int nfull = deg >> 4;
    const int tail  = deg & 15;

    // prefetch weight-phase inputs (colv, a) for tile 0
    int   colv = 0;
    float a    = 0.f;
    {
        const int cnt0 = (nfull > 0) ? 16 : tail;
        if (eoff < cnt0) {
            colv = col[k0 + eoff];
            a    = as_[colv * H + head];
        }
    }

    int k = k0;
    for (int t = 0; t < nfull; ++t, k += 16) {
        // weight phase for current (full) tile from prefetched (colv, a)
        float le = a + adn;
        le = fmaxf(le, NEG * le);
        const float w = __expf(le);
        den += w;
        wrow[lane] = w;
        const int colc = colv;

        // issue 16 hb gather loads (saddr via readlane, shared voffset)
        u32 v[16];
#pragma unroll
        for (int e = 0; e < 16; ++e) {
            const int s = __builtin_amdgcn_readlane(colc, e);
            v[e] = hb[s * 64 + lane];
        }

        // prefetch next tile's weight inputs while loads are in flight
        const int cntn = (t + 1 < nfull) ? 16 : tail;
        if (eoff < cntn) {
            colv = col[k + 16 + eoff];
            a    = as_[colv * H + head];
        } else {
            colv = 0;
        }

        // consume: w broadcast via ds_read_b128, 2 fma + 2 unpack per edge-lane
#pragma unroll
        for (int e = 0; e < 16; e += 4) {
            const float4 w4 = *(const float4*)(wrow + wbase + e);
            num0 = fmaf(w4.x, lo16(v[e + 0]), num0); num1 = fmaf(w4.x, hi16(v[e + 0]), num1);
            num0 = fmaf(w4.y, lo16(v[e + 1]), num0); num1 = fmaf(w4.y, hi16(v[e + 1]), num1);
            num0 = fmaf(w4.z, lo16(v[e + 2]), num0); num1 = fmaf(w4.z, hi16(v[e + 2]), num1);
            num0 = fmaf(w4.w, lo16(v[e + 3]), num0); num1 = fmaf(w4.w, hi16(v[e + 3]), num1);
        }
    }

    if (tail) {
        // weight phase for tail tile (masked lanes contribute w = 0)
        float le = a + adn;
        le = fmaxf(le, NEG * le);
        const float w = (eoff < tail) ? __expf(le) : 0.f;
        den += w;
        wrow[lane] = w;
        const int colc = colv;

        int e = 0;
        for (; e + 4 <= tail; e += 4) {
            const float4 w4 = *(const float4*)(wrow + wbase + e);
            const int s0 = __builtin_amdgcn_readlane(colc, e + 0);
            const int s1 = __builtin_amdgcn_readlane(colc, e + 1);
            const int s2 = __builtin_amdgcn_readlane(colc, e + 2);
            const int s3 = __builtin_amdgcn_readlane(colc, e + 3);
            const u32 v0 = hb[s0 * 64 + lane];
            const u32 v1 = hb[s1 * 64 + lane];
            const u32 v2 = hb[s2 * 64 + lane];
            const u32 v3 = hb[s3 * 64 + lane];
            num0 = fmaf(w4.x, lo16(v0), num0); num1 = fmaf(w4.x, hi16(v0), num1);
            num0 = fmaf(w4.y, lo16(v1), num0); num1 = fmaf(w4.y, hi16(v1), num1);
            num0 = fmaf(w4.z, lo16(v2), num0); num1 = fmaf(w4.z, hi16(v2), num1);
            num0 = fmaf(w4.w, lo16(v3), num0); num1 = fmaf(w4.w, hi16(v3), num1);
        }
        for (; e < tail; ++e) {
            const float we = wrow[wbase + e];
            const int  s  = __builtin_amdgcn_readlane(colc, e);
            const u32  vv = hb[s * 64 + lane];
            num0 = fmaf(we, lo16(vv), num0);
            num1 = fmaf(we, hi16(vv), num1);
        }
    }

    // reduce den partials across the 16 lanes of each head group
#pragma unroll
    for (int off = 1; off < 16; off <<= 1) den += __shfl_xor(den, off, 64);

    const int c0 = lane * 2;
    const float inv_den = 1.f / (den + SEPS);
    const float2 bi = *(const float2*)(bias + c0);
    float v0 = num0 * inv_den + bi.x;
    float v1 = num1 * inv_den + bi.y;

    float sum = v0 + v1;
#pragma unroll
    for (int off = 32; off; off >>= 1) sum += __shfl_xor(sum, off, 64);
    const float mu = sum * (1.0f / C);
    const float d0 = v0 - mu, d1 = v1 - mu;
    float sq = d0 * d0 + d1 * d1;
#pragma unroll
    for (int off = 32; off; off >>= 1) sq += __shfl_xor(sq, off, 64);
    const float inv = rsqrtf(sq * (1.0f / C) + LEPS);
    const float2 ga = *(const float2*)(gamma + c0);
    const float2 be = *(const float2*)(beta  + c0);
    float y0 = d0 * inv * ga.x + be.x;
    float y1 = d1 * inv * ga.y + be.y;
    y0 = y0 > 0.f ? y0 : __expf(y0) - 1.f;
    y1 = y1 > 0.f ? y1 : __expf(y1) - 1.f;
    float2 o; o.x = y0; o.y = y1;
    *(float2*)(out + (size_t)n * C + c0) = o;
}

extern "C" void kernel_launch(void* const* d_in, const int* in_sizes, int n_in,
                              void* d_out, int out_size, void* d_ws, size_t ws_size,
                              hipStream_t stream)
{
    const float* x     = (const float*)d_in[0];
    const int*   ei    = (const int*)  d_in[1];
    const float* W     = (const float*)d_in[2];
    const float* att_s = (const float*)d_in[3];
    const float* att_d = (const float*)d_in[4];
    const float* bias  = (const float*)d_in[5];
    const float* gamma = (const float*)d_in[6];
    const float* beta  = (const float*)d_in[7];
    float* out = (float*)d_out;

    // ws (~26 MB): hb bf16[N*C] | as_ | ad_ | pairs u32[NB*CAP] | col u16[E]
    //            | row_ptr int[N+1] | gcur u32[NB] | bbase u32[NB]
    char* p = (char*)d_ws;
    bf16*  hb      = (bf16*)p;   p += (size_t)N * C * sizeof(bf16);
    float* as_     = (float*)p;  p += (size_t)N * H * sizeof(float);
    float* ad_     = (float*)p;  p += (size_t)N * H * sizeof(float);
    u32*   pairs   = (u32*)p;    p += (size_t)NB * CAP * sizeof(u32);
    u16*   col     = (u16*)p;    p += ((size_t)E * sizeof(u16) + 15) & ~(size_t)15;
    int*   row_ptr = (int*)p;    p += ((size_t)(N + 1) * sizeof(int) + 15) & ~(size_t)15;
    u32*   gcur    = (u32*)p;    p += (size_t)NB * sizeof(u32);
    u32*   bbase   = (u32*)p;

    hipMemsetAsync(gcur, 0, NB * sizeof(u32), stream);
    k1_gemm<<<N / 16, 256, 0, stream>>>(x, W, att_s, att_d, hb, as_, ad_);
    kbin<<<(E + CHUNK - 1) / CHUNK, 256, 0, stream>>>(ei, gcur, pairs);
    kscan<<<1, 64, 0, stream>>>(gcur, bbase, row_ptr);
    kfill2<<<NB, 256, 0, stream>>>(pairs, gcur, bbase, row_ptr, col);
    kd_agg_ln<<<(N * 64) / 256, 256, 0, stream>>>(
        row_ptr, col, (const u32*)hb, as_, ad_, bias, gamma, beta, out);
}

// Round 3
// 231.733 us; speedup vs baseline: 1.0587x; 1.0311x over previous
//
#include <hip/hip_runtime.h>
#include <hip/hip_bf16.h>

typedef __hip_bfloat16 bf16;
typedef unsigned int u32;
typedef unsigned short u16;

constexpr int N   = 50000;
constexpr int E   = 1600000;
constexpr int C   = 128;             // channels (H * 32)
constexpr int H   = 4;               // heads
constexpr int NB  = 782;             // dst buckets of 64 nodes (782*64 >= 50000)
constexpr int CAP = 2560;            // pairs capacity per bucket (mean 2048, +11 sigma)
constexpr int CHUNK = 4096;          // edges per kbin block
constexpr float NEG  = 0.2f;
constexpr float SEPS = 1e-16f;
constexpr float LEPS = 1e-5f;

__device__ __forceinline__ float lo16(u32 v) { return __uint_as_float(v << 16); }
__device__ __forceinline__ float hi16(u32 v) { return __uint_as_float(v & 0xFFFF0000u); }

// K1: h = x @ W, 16 nodes per block. x tile in LDS; W from global (L1/L2-hot).
// h stored bf16. Fused attention dots a_s, a_d.
__global__ __launch_bounds__(256) void k1_gemm(
    const float* __restrict__ x, const float* __restrict__ W,
    const float* __restrict__ att_s, const float* __restrict__ att_d,
    bf16* __restrict__ hb, float* __restrict__ as_, float* __restrict__ ad_)
{
    const int nb = blockIdx.x * 16;
    const int t  = threadIdx.x;
    __shared__ float sx[16 * 128];
    const float4* xg = (const float4*)(x + nb * 128);
    ((float4*)sx)[t]       = xg[t];
    ((float4*)sx)[t + 256] = xg[t + 256];
    __syncthreads();

    const int c = t & 127;           // output channel
    const int g = t >> 7;            // node group (0/1) of 8 nodes
    const float* xb = sx + (g << 10);
    float acc[8] = {0.f, 0.f, 0.f, 0.f, 0.f, 0.f, 0.f, 0.f};

    for (int k = 0; k < 128; k += 4) {
        const float w0 = W[(k + 0) * 128 + c];
        const float w1 = W[(k + 1) * 128 + c];
        const float w2 = W[(k + 2) * 128 + c];
        const float w3 = W[(k + 3) * 128 + c];
#pragma unroll
        for (int j = 0; j < 8; ++j) {
            const float4 xv = *(const float4*)(xb + j * 128 + k);
            acc[j] = fmaf(xv.x, w0, fmaf(xv.y, w1, fmaf(xv.z, w2, fmaf(xv.w, w3, acc[j]))));
        }
    }

    const int lane = t & 63;
    const int head = c >> 5;
    const float asc = att_s[c], adc = att_d[c];
#pragma unroll
    for (int j = 0; j < 8; ++j) {
        const int node = nb + (g << 3) + j;
        hb[node * 128 + c] = __float2bfloat16(acc[j]);
        float vs = acc[j] * asc;
        float vd = acc[j] * adc;
#pragma unroll
        for (int off = 16; off; off >>= 1) {
            vs += __shfl_xor(vs, off, 64);
            vd += __shfl_xor(vd, off, 64);
        }
        if ((lane & 31) == 0) {
            as_[node * H + head] = vs;
            ad_[node * H + head] = vd;
        }
    }
}

// KBIN: bin edges into NB dst-buckets as packed u32 (src | (dst&63)<<16).
// Two-phase per chunk: LDS int count -> global reserve -> scatter.
// Bucket runs are temporally clustered -> L2 merges write lines.
__global__ __launch_bounds__(256) void kbin(
    const int* __restrict__ ei, u32* __restrict__ gcur, u32* __restrict__ pairs)
{
    __shared__ u32 lcnt[NB], lbase[NB], lfill[NB];
    const int t = threadIdx.x;
    const int base = blockIdx.x * CHUNK;
    const int nE = min(CHUNK, E - base);
    for (int i = t; i < NB; i += 256) lcnt[i] = 0;
    __syncthreads();
    for (int i = t; i < nE; i += 256)
        atomicAdd(&lcnt[((u32)ei[E + base + i]) >> 6], 1u);
    __syncthreads();
    for (int i = t; i < NB; i += 256) {
        u32 cb = lcnt[i];
        lbase[i] = cb ? atomicAdd(&gcur[i], cb) : 0u;
        lfill[i] = 0u;
    }
    __syncthreads();
    for (int i = t; i < nE; i += 256) {
        u32 src = (u32)ei[base + i];
        u32 dst = (u32)ei[E + base + i];
        u32 b = dst >> 6;
        u32 pos = atomicAdd(&lfill[b], 1u);
        pairs[(size_t)b * CAP + lbase[b] + pos] = src | ((dst & 63u) << 16);
    }
}

// KSCAN: one wave — exclusive scan of gcur[NB] -> bbase; row_ptr[N] = E.
__global__ __launch_bounds__(64) void kscan(
    const u32* __restrict__ gcur, u32* __restrict__ bbase, int* __restrict__ row_ptr)
{
    const int t = threadIdx.x;
    u32 vals[13];
    u32 s = 0;
#pragma unroll
    for (int i = 0; i < 13; ++i) {
        int idx = t * 13 + i;
        u32 v = (idx < NB) ? gcur[idx] : 0u;
        vals[i] = s; s += v;
    }
    u32 incl = s;
#pragma unroll
    for (int off = 1; off < 64; off <<= 1) {
        u32 u = __shfl_up(incl, off, 64);
        if (t >= off) incl += u;
    }
    const u32 excl = incl - s;
#pragma unroll
    for (int i = 0; i < 13; ++i) {
        int idx = t * 13 + i;
        if (idx < NB) bbase[idx] = excl + vals[i];
    }
    if (t == 0) row_ptr[N] = E;
}

// KFILL2: block per bucket. Count per node (int LDS atomics), wave scan,
// write row_ptr and scatter u16 col within the bucket's narrow region.
__global__ __launch_bounds__(256) void kfill2(
    const u32* __restrict__ pairs, const u32* __restrict__ gcur,
    const u32* __restrict__ bbase, int* __restrict__ row_ptr, u16* __restrict__ col)
{
    __shared__ int jcnt[64], joff[64], jcur[64];
    const int b = blockIdx.x, t = threadIdx.x;
    const int cntb = (int)gcur[b];
    const int base = (int)bbase[b];
    if (t < 64) jcnt[t] = 0;
    __syncthreads();
    const u32* pr = pairs + (size_t)b * CAP;
    for (int i = t; i < cntb; i += 256) atomicAdd(&jcnt[pr[i] >> 16], 1);
    __syncthreads();
    if (t < 64) {
        int v = jcnt[t], incl = v;
#pragma unroll
        for (int off = 1; off < 64; off <<= 1) {
            int u = __shfl_up(incl, off, 64);
            if (t >= off) incl += u;
        }
        joff[t] = incl - v;
        const int n = b * 64 + t;
        if (n < N) row_ptr[n] = base + joff[t];
        jcur[t] = 0;
    }
    __syncthreads();
    for (int i = t; i < cntb; i += 256) {
        const u32 p = pr[i];
        const int j = p >> 16;
        const int pos = atomicAdd(&jcur[j], 1);
        col[base + joff[j] + pos] = (u16)(p & 0xFFFFu);
    }
}

// KD v4: fused attention-softmax aggregation + bias + LayerNorm + ELU.
// One wave per node, uniform full-16 tiles (masked weights for the ragged
// last tile; masked lanes gather the L1-hot row 0 of hb).
//   - scalar addressing: readlane(col) -> uniform row pointer (SGPR base,
//     shared lane*4 voffset) -> 1 VALU per gather
//   - 16 named loads + sched_barrier(0) fences: all 16 stay in flight
//   - weight inputs pipelined 2 tiles deep (col @ t+2, as_ @ t+1), so no
//     dependent col->as_ stall sits on the critical path
//   - col reads branchless via 64-entry pad on the col allocation
__global__ __launch_bounds__(256) void kd_agg_ln(
    const int* __restrict__ row_ptr, const u16* __restrict__ col,
    const u32* __restrict__ hb, const float* __restrict__ as_,
    const float* __restrict__ ad_,
    const float* __restrict__ bias, const float* __restrict__ gamma,
    const float* __restrict__ beta, float* __restrict__ out)
{
    __shared__ float wlds[4][64];
    const int tid  = threadIdx.x;
    const int lane = tid & 63;
    const int wv   = __builtin_amdgcn_readfirstlane(tid >> 6);
    const int n    = __builtin_amdgcn_readfirstlane((int)blockIdx.x * 4 + (tid >> 6));
    if (n >= N) return;

    const int head  = lane >> 4;   // weight phase: head; accumulation: (lane*2)>>5 == same
    const int eoff  = lane & 15;   // weight phase: edge slot within tile
    const int wbase = head << 4;
    float* __restrict__ wrow = wlds[wv];

    const float adn = ad_[n * H + head];
    const float asn = as_[n * H + head];

    // self-loop (src == dst == n); every lane holds w_self for its own head
    float ls = asn + adn;
    ls = fmaxf(ls, NEG * ls);
    const float wself = __expf(ls);
    float den = (eoff == 0) ? wself : 0.f;   // count self-loop once per head group
    const u32 hvs = hb[n * 64 + lane];
    float num0 = wself * lo16(hvs);
    float num1 = wself * hi16(hvs);

    const int k0  = row_ptr[n];
    const int deg = row_ptr[n + 1] - k0;
    const int ntiles = (deg + 15) >> 4;

    // prologue: weight-phase inputs for tiles 0 and 1 (col reads rely on pad)
    const int cnt0 = deg < 16 ? deg : 16;
    const int cnt1 = (deg - 16) < 16 ? (deg - 16) : 16;
    int colv_cur = (eoff < cnt0) ? (int)col[k0 + eoff]      : 0;
    int colv_nxt = (eoff < cnt1) ? (int)col[k0 + 16 + eoff] : 0;
    float a_cur  = as_[colv_cur * H + head];   // masked lanes read as_[head] (hot)
    int cntc = cnt0, cntn = cnt1;

    int k = k0;
    for (int t = 0; t < ntiles; ++t, k += 16) {
        // issue col gather for tile t+2 (no dependence on anything in flight)
        const int rem2 = deg - 16 * (t + 2);
        const int cnt2 = rem2 < 16 ? rem2 : 16;
        const int cf_raw = (int)col[k + 32 + eoff];        // padded: always in-bounds
        const int colv_f = (eoff < cnt2) ? cf_raw : 0;

        // weight phase for tile t (a_cur loaded a full tile ago)
        float le = a_cur + adn;
        le = fmaxf(le, NEG * le);
        const float w = (eoff < cntc) ? __expf(le) : 0.f;  // mask kills ragged tail
        den += w;
        wrow[lane] = w;
        const int colc = colv_cur;

        // 16 gather loads, scalar base per edge, all in flight before consume
#define GL(i) const u32* rp##i = hb + ((size_t)(u32)__builtin_amdgcn_readlane(colc, i) << 6); \
              const u32 v##i = rp##i[lane];
        GL(0) GL(1) GL(2) GL(3) GL(4) GL(5) GL(6) GL(7)
        GL(8) GL(9) GL(10) GL(11) GL(12) GL(13) GL(14) GL(15)
#undef GL
        __builtin_amdgcn_sched_barrier(0);

        // issue as_ gather for tile t+1 (colv_nxt resident since last tile)
        const float a_n = as_[colv_nxt * H + head];
        __builtin_amdgcn_sched_barrier(0);

        // consume: w broadcast via ds_read_b128, 2 fma + 2 unpack per edge-lane
        {
            const float4 wa = *(const float4*)(wrow + wbase + 0);
            num0 = fmaf(wa.x, lo16(v0), num0);  num1 = fmaf(wa.x, hi16(v0), num1);
            num0 = fmaf(wa.y, lo16(v1), num0);  num1 = fmaf(wa.y, hi16(v1), num1);
            num0 = fmaf(wa.z, lo16(v2), num0);  num1 = fmaf(wa.z, hi16(v2), num1);
            num0 = fmaf(wa.w, lo16(v3), num0);  num1 = fmaf(wa.w, hi16(v3), num1);
            const float4 wb = *(const float4*)(wrow + wbase + 4);
            num0 = fmaf(wb.x, lo16(v4), num0);  num1 = fmaf(wb.x, hi16(v4), num1);
            num0 = fmaf(wb.y, lo16(v5), num0);  num1 = fmaf(wb.y, hi16(v5), num1);
            num0 = fmaf(wb.z, lo16(v6), num0);  num1 = fmaf(wb.z, hi16(v6), num1);
            num0 = fmaf(wb.w, lo16(v7), num0);  num1 = fmaf(wb.w, hi16(v7), num1);
            const float4 wc = *(const float4*)(wrow + wbase + 8);
            num0 = fmaf(wc.x, lo16(v8), num0);  num1 = fmaf(wc.x, hi16(v8), num1);
            num0 = fmaf(wc.y, lo16(v9), num0);  num1 = fmaf(wc.y, hi16(v9), num1);
            num0 = fmaf(wc.z, lo16(v10), num0); num1 = fmaf(wc.z, hi16(v10), num1);
            num0 = fmaf(wc.w, lo16(v11), num0); num1 = fmaf(wc.w, hi16(v11), num1);
            const float4 wd = *(const float4*)(wrow + wbase + 12);
            num0 = fmaf(wd.x, lo16(v12), num0); num1 = fmaf(wd.x, hi16(v12), num1);
            num0 = fmaf(wd.y, lo16(v13), num0); num1 = fmaf(wd.y, hi16(v13), num1);
            num0 = fmaf(wd.z, lo16(v14), num0); num1 = fmaf(wd.z, hi16(v14), num1);
            num0 = fmaf(wd.w, lo16(v15), num0); num1 = fmaf(wd.w, hi16(v15), num1);
        }

        // rotate pipeline state
        colv_cur = colv_nxt; colv_nxt = colv_f;
        a_cur = a_n;
        cntc = cntn; cntn = cnt2;
    }

    // reduce den partials across the 16 lanes of each head group
#pragma unroll
    for (int off = 1; off < 16; off <<= 1) den += __shfl_xor(den, off, 64);

    const int c0 = lane * 2;
    const float inv_den = 1.f / (den + SEPS);
    const float2 bi = *(const float2*)(bias + c0);
    float v0 = num0 * inv_den + bi.x;
    float v1 = num1 * inv_den + bi.y;

    float sum = v0 + v1;
#pragma unroll
    for (int off = 32; off; off >>= 1) sum += __shfl_xor(sum, off, 64);
    const float mu = sum * (1.0f / C);
    const float d0 = v0 - mu, d1 = v1 - mu;
    float sq = d0 * d0 + d1 * d1;
#pragma unroll
    for (int off = 32; off; off >>= 1) sq += __shfl_xor(sq, off, 64);
    const float inv = rsqrtf(sq * (1.0f / C) + LEPS);
    const float2 ga = *(const float2*)(gamma + c0);
    const float2 be = *(const float2*)(beta  + c0);
    float y0 = d0 * inv * ga.x + be.x;
    float y1 = d1 * inv * ga.y + be.y;
    y0 = y0 > 0.f ? y0 : __expf(y0) - 1.f;
    y1 = y1 > 0.f ? y1 : __expf(y1) - 1.f;
    float2 o; o.x = y0; o.y = y1;
    *(float2*)(out + (size_t)n * C + c0) = o;
}

extern "C" void kernel_launch(void* const* d_in, const int* in_sizes, int n_in,
                              void* d_out, int out_size, void* d_ws, size_t ws_size,
                              hipStream_t stream)
{
    const float* x     = (const float*)d_in[0];
    const int*   ei    = (const int*)  d_in[1];
    const float* W     = (const float*)d_in[2];
    const float* att_s = (const float*)d_in[3];
    const float* att_d = (const float*)d_in[4];
    const float* bias  = (const float*)d_in[5];
    const float* gamma = (const float*)d_in[6];
    const float* beta  = (const float*)d_in[7];
    float* out = (float*)d_out;

    // ws (~26 MB): hb bf16[N*C] | as_ | ad_ | pairs u32[NB*CAP] | col u16[E+64]
    //            | row_ptr int[N+1] | gcur u32[NB] | bbase u32[NB]
    char* p = (char*)d_ws;
    bf16*  hb      = (bf16*)p;   p += (size_t)N * C * sizeof(bf16);
    float* as_     = (float*)p;  p += (size_t)N * H * sizeof(float);
    float* ad_     = (float*)p;  p += (size_t)N * H * sizeof(float);
    u32*   pairs   = (u32*)p;    p += (size_t)NB * CAP * sizeof(u32);
    u16*   col     = (u16*)p;    p += ((size_t)(E + 64) * sizeof(u16) + 15) & ~(size_t)15;
    int*   row_ptr = (int*)p;    p += ((size_t)(N + 1) * sizeof(int) + 15) & ~(size_t)15;
    u32*   gcur    = (u32*)p;    p += (size_t)NB * sizeof(u32);
    u32*   bbase   = (u32*)p;

    hipMemsetAsync(gcur, 0, NB * sizeof(u32), stream);
    k1_gemm<<<N / 16, 256, 0, stream>>>(x, W, att_s, att_d, hb, as_, ad_);
    kbin<<<(E + CHUNK - 1) / CHUNK, 256, 0, stream>>>(ei, gcur, pairs);
    kscan<<<1, 64, 0, stream>>>(gcur, bbase, row_ptr);
    kfill2<<<NB, 256, 0, stream>>>(pairs, gcur, bbase, row_ptr, col);
    kd_agg_ln<<<(N * 64) / 256, 256, 0, stream>>>(
        row_ptr, col, (const u32*)hb, as_, ad_, bias, gamma, beta, out);
}

// Round 4
// 223.725 us; speedup vs baseline: 1.0966x; 1.0358x over previous
//
#include <hip/hip_runtime.h>
#include <hip/hip_bf16.h>

typedef __hip_bfloat16 bf16;
typedef unsigned int u32;
typedef unsigned short u16;
typedef __attribute__((ext_vector_type(8))) short bf16x8;
typedef __attribute__((ext_vector_type(4))) float f32x4;

constexpr int N   = 50000;
constexpr int E   = 1600000;
constexpr int C   = 128;             // channels (H * 32)
constexpr int H   = 4;               // heads
constexpr int NB  = 782;             // dst buckets of 64 nodes (782*64 >= 50000)
constexpr int CAP = 2560;            // pairs capacity per bucket (mean 2048, +11 sigma)
constexpr int CHUNK = 6250;          // edges per kbin block (256 persistent blocks)
constexpr float NEG  = 0.2f;
constexpr float SEPS = 1e-16f;
constexpr float LEPS = 1e-5f;

__device__ __forceinline__ float lo16(u32 v) { return __uint_as_float(v << 16); }
__device__ __forceinline__ float hi16(u32 v) { return __uint_as_float(v & 0xFFFF0000u); }
__device__ __forceinline__ u16 bfbits(float f) {
    __hip_bfloat16 h = __float2bfloat16(f);
    return *reinterpret_cast<u16*>(&h);
}

// K0: W f32[k][c] (128x128) -> W_t hi/lo bf16[c][k] (split precision).
__global__ __launch_bounds__(256) void k0_wprep(
    const float* __restrict__ W, u16* __restrict__ wt_hi, u16* __restrict__ wt_lo)
{
    const int i = blockIdx.x * 256 + threadIdx.x;   // 64 blocks x 256 = 16384
    const int c = i >> 7, k = i & 127;
    const float w = W[k * 128 + c];
    const __hip_bfloat16 h = __float2bfloat16(w);
    const float fh = __bfloat162float(h);
    wt_hi[i] = *(const u16*)&h;
    wt_lo[i] = bfbits(w - fh);
}

// K1 (MFMA): h = x @ W via split-bf16 (x_hi+x_lo, W_hi+W_lo; 3 mfma terms).
// 64 nodes/block, 4 waves, each wave a 16-row slice x 128 cols.
// x staged in LDS (bf16 hi/lo, +8 elem row pad -> 2-way bank alias, free).
// B frags streamed from L2-hot 64KB W_t. Fused att dots + bf16 hb store.
__global__ __launch_bounds__(256) void k1_mfma(
    const float* __restrict__ x,
    const u16* __restrict__ wt_hi, const u16* __restrict__ wt_lo,
    const float* __restrict__ att_s, const float* __restrict__ att_d,
    u16* __restrict__ hb, float* __restrict__ as_, float* __restrict__ ad_)
{
    constexpr int LDX = 136;                  // row stride in bf16 elems (128+8)
    __shared__ u16 xhi[64 * LDX];
    __shared__ u16 xlo[64 * LDX];
    const int t  = threadIdx.x;
    const int m0 = blockIdx.x * 64;

    // stage x tile: 64 rows x 128 f32, clamp OOB rows to last valid row
#pragma unroll
    for (int it = 0; it < 8; ++it) {
        const int idx = it * 1024 + t * 4;    // element index (float granule of 4)
        const int r = idx >> 7, c = idx & 127;
        const int gr = min(m0 + r, N - 1);
        const float4 v = *(const float4*)(x + (size_t)gr * 128 + c);
        ushort4 sh, sl;
        {
            __hip_bfloat16 h0 = __float2bfloat16(v.x);
            __hip_bfloat16 h1 = __float2bfloat16(v.y);
            __hip_bfloat16 h2 = __float2bfloat16(v.z);
            __hip_bfloat16 h3 = __float2bfloat16(v.w);
            sh.x = *(u16*)&h0; sh.y = *(u16*)&h1; sh.z = *(u16*)&h2; sh.w = *(u16*)&h3;
            sl.x = bfbits(v.x - __bfloat162float(h0));
            sl.y = bfbits(v.y - __bfloat162float(h1));
            sl.z = bfbits(v.z - __bfloat162float(h2));
            sl.w = bfbits(v.w - __bfloat162float(h3));
        }
        *(ushort4*)(xhi + r * LDX + c) = sh;
        *(ushort4*)(xlo + r * LDX + c) = sl;
    }
    __syncthreads();

    const int lane = t & 63;
    const int w    = t >> 6;                  // wave id: rows [w*16, w*16+16)
    const int arow = w * 16 + (lane & 15);
    const int akg  = lane >> 4;               // k-group 0..3 (8 elems each)
    const int bcol = lane & 15;               // col within n-tile
    const int aq   = lane >> 4;               // C/D row quarter

    // A fragments: hi and lo for 4 K-steps (K=128 = 4 x 32)
    bf16x8 Ah[4], Al[4];
#pragma unroll
    for (int ks = 0; ks < 4; ++ks) {
        Ah[ks] = *(const bf16x8*)(xhi + arow * LDX + ks * 32 + akg * 8);
        Al[ks] = *(const bf16x8*)(xlo + arow * LDX + ks * 32 + akg * 8);
    }

    f32x4 acc[8];
#pragma unroll
    for (int nt = 0; nt < 8; ++nt) acc[nt] = f32x4{0.f, 0.f, 0.f, 0.f};

#pragma unroll
    for (int nt = 0; nt < 8; ++nt) {
        const u16* bp = wt_hi + (nt * 16 + bcol) * 128 + akg * 8;
        const u16* bq = wt_lo + (nt * 16 + bcol) * 128 + akg * 8;
#pragma unroll
        for (int ks = 0; ks < 4; ++ks) {
            const bf16x8 Bh = *(const bf16x8*)(bp + ks * 32);
            const bf16x8 Bl = *(const bf16x8*)(bq + ks * 32);
            acc[nt] = __builtin_amdgcn_mfma_f32_16x16x32_bf16(Ah[ks], Bh, acc[nt], 0, 0, 0);
            acc[nt] = __builtin_amdgcn_mfma_f32_16x16x32_bf16(Al[ks], Bh, acc[nt], 0, 0, 0);
            acc[nt] = __builtin_amdgcn_mfma_f32_16x16x32_bf16(Ah[ks], Bl, acc[nt], 0, 0, 0);
        }
    }

    // hb store: C/D layout col=lane&15, row=(lane>>4)*4+reg  [m89/m91]
#pragma unroll
    for (int nt = 0; nt < 8; ++nt) {
        const int ch = nt * 16 + bcol;
#pragma unroll
        for (int r = 0; r < 4; ++r) {
            const int node = m0 + w * 16 + aq * 4 + r;
            if (node < N) hb[(size_t)node * 128 + ch] = bfbits(acc[nt][r]);
        }
    }

    // fused attention dots: per (node, head) sum over the head's 32 channels
    float ps[4][4], pd[4][4];                 // [head][r]
#pragma unroll
    for (int h = 0; h < 4; ++h) {
        const float a0 = att_s[32 * h + bcol],      a1 = att_s[32 * h + 16 + bcol];
        const float d0 = att_d[32 * h + bcol],      d1 = att_d[32 * h + 16 + bcol];
#pragma unroll
        for (int r = 0; r < 4; ++r) {
            ps[h][r] = acc[2 * h][r] * a0 + acc[2 * h + 1][r] * a1;
            pd[h][r] = acc[2 * h][r] * d0 + acc[2 * h + 1][r] * d1;
        }
    }
#pragma unroll
    for (int off = 1; off < 16; off <<= 1) {
#pragma unroll
        for (int h = 0; h < 4; ++h)
#pragma unroll
            for (int r = 0; r < 4; ++r) {
                ps[h][r] += __shfl_xor(ps[h][r], off, 64);
                pd[h][r] += __shfl_xor(pd[h][r], off, 64);
            }
    }
    if (bcol == 0) {
#pragma unroll
        for (int r = 0; r < 4; ++r) {
            const int node = m0 + w * 16 + aq * 4 + r;
            if (node < N) {
#pragma unroll
                for (int h = 0; h < 4; ++h) {
                    as_[node * H + h] = ps[h][r];
                    ad_[node * H + h] = pd[h][r];
                }
            }
        }
    }
}

// KBIN: bin edges into NB dst-buckets as packed u32 (src | (dst&63)<<16).
// 256 persistent blocks (fewer contended global reservation atomics).
__global__ __launch_bounds__(256) void kbin(
    const int* __restrict__ ei, u32* __restrict__ gcur, u32* __restrict__ pairs)
{
    __shared__ u32 lcnt[NB], lbase[NB], lfill[NB];
    const int t = threadIdx.x;
    const int base = blockIdx.x * CHUNK;
    const int nE = min(CHUNK, E - base);
    for (int i = t; i < NB; i += 256) lcnt[i] = 0;
    __syncthreads();
    for (int i = t; i < nE; i += 256)
        atomicAdd(&lcnt[((u32)ei[E + base + i]) >> 6], 1u);
    __syncthreads();
    for (int i = t; i < NB; i += 256) {
        u32 cb = lcnt[i];
        lbase[i] = cb ? atomicAdd(&gcur[i], cb) : 0u;
        lfill[i] = 0u;
    }
    __syncthreads();
    for (int i = t; i < nE; i += 256) {
        u32 src = (u32)ei[base + i];
        u32 dst = (u32)ei[E + base + i];
        u32 b = dst >> 6;
        u32 pos = atomicAdd(&lfill[b], 1u);
        pairs[(size_t)b * CAP + lbase[b] + pos] = src | ((dst & 63u) << 16);
    }
}

// KSCAN: one wave — exclusive scan of gcur[NB] -> bbase; row_ptr[N] = E.
__global__ __launch_bounds__(64) void kscan(
    const u32* __restrict__ gcur, u32* __restrict__ bbase, int* __restrict__ row_ptr)
{
    const int t = threadIdx.x;
    u32 vals[13];
    u32 s = 0;
#pragma unroll
    for (int i = 0; i < 13; ++i) {
        int idx = t * 13 + i;
        u32 v = (idx < NB) ? gcur[idx] : 0u;
        vals[i] = s; s += v;
    }
    u32 incl = s;
#pragma unroll
    for (int off = 1; off < 64; off <<= 1) {
        u32 u = __shfl_up(incl, off, 64);
        if (t >= off) incl += u;
    }
    const u32 excl = incl - s;
#pragma unroll
    for (int i = 0; i < 13; ++i) {
        int idx = t * 13 + i;
        if (idx < NB) bbase[idx] = excl + vals[i];
    }
    if (t == 0) row_ptr[N] = E;
}

// KFILL2: block per bucket. Pairs staged once in LDS; count + scan + scatter
// all against LDS; col written back coalesced from an LDS staging buffer.
__global__ __launch_bounds__(256) void kfill2(
    const u32* __restrict__ pairs, const u32* __restrict__ gcur,
    const u32* __restrict__ bbase, int* __restrict__ row_ptr, u16* __restrict__ col)
{
    __shared__ u32 spr[CAP];
    __shared__ u16 scol[CAP];
    __shared__ int jcnt[64], joff[64], jcur[64];
    const int b = blockIdx.x, t = threadIdx.x;
    const int cntb = (int)gcur[b];
    const int base = (int)bbase[b];
    if (t < 64) jcnt[t] = 0;
    const u32* pr = pairs + (size_t)b * CAP;
    for (int i = t; i < cntb; i += 256) spr[i] = pr[i];
    __syncthreads();
    for (int i = t; i < cntb; i += 256) atomicAdd(&jcnt[spr[i] >> 16], 1);
    __syncthreads();
    if (t < 64) {
        int v = jcnt[t], incl = v;
#pragma unroll
        for (int off = 1; off < 64; off <<= 1) {
            int u = __shfl_up(incl, off, 64);
            if (t >= off) incl += u;
        }
        joff[t] = incl - v;
        const int n = b * 64 + t;
        if (n < N) row_ptr[n] = base + joff[t];
        jcur[t] = 0;
    }
    __syncthreads();
    for (int i = t; i < cntb; i += 256) {
        const u32 p = spr[i];
        const int j = p >> 16;
        const int pos = atomicAdd(&jcur[j], 1);
        scol[joff[j] + pos] = (u16)(p & 0xFFFFu);
    }
    __syncthreads();
    for (int i = t; i < cntb; i += 256) col[base + i] = scol[i];
}

// KD v4 (unchanged from R3 — control for this round's preprocessing changes).
__global__ __launch_bounds__(256) void kd_agg_ln(
    const int* __restrict__ row_ptr, const u16* __restrict__ col,
    const u32* __restrict__ hb, const float* __restrict__ as_,
    const float* __restrict__ ad_,
    const float* __restrict__ bias, const float* __restrict__ gamma,
    const float* __restrict__ beta, float* __restrict__ out)
{
    __shared__ float wlds[4][64];
    const int tid  = threadIdx.x;
    const int lane = tid & 63;
    const int wv   = __builtin_amdgcn_readfirstlane(tid >> 6);
    const int n    = __builtin_amdgcn_readfirstlane((int)blockIdx.x * 4 + (tid >> 6));
    if (n >= N) return;

    const int head  = lane >> 4;
    const int eoff  = lane & 15;
    const int wbase = head << 4;
    float* __restrict__ wrow = wlds[wv];

    const float adn = ad_[n * H + head];
    const float asn = as_[n * H + head];

    float ls = asn + adn;
    ls = fmaxf(ls, NEG * ls);
    const float wself = __expf(ls);
    float den = (eoff == 0) ? wself : 0.f;
    const u32 hvs = hb[n * 64 + lane];
    float num0 = wself * lo16(hvs);
    float num1 = wself * hi16(hvs);

    const int k0  = row_ptr[n];
    const int deg = row_ptr[n + 1] - k0;
    const int ntiles = (deg + 15) >> 4;

    const int cnt0 = deg < 16 ? deg : 16;
    const int cnt1 = (deg - 16) < 16 ? (deg - 16) : 16;
    int colv_cur = (eoff < cnt0) ? (int)col[k0 + eoff]      : 0;
    int colv_nxt = (eoff < cnt1) ? (int)col[k0 + 16 + eoff] : 0;
    float a_cur  = as_[colv_cur * H + head];
    int cntc = cnt0, cntn = cnt1;

    int k = k0;
    for (int t = 0; t < ntiles; ++t, k += 16) {
        const int rem2 = deg - 16 * (t + 2);
        const int cnt2 = rem2 < 16 ? rem2 : 16;
        const int cf_raw = (int)col[k + 32 + eoff];
        const int colv_f = (eoff < cnt2) ? cf_raw : 0;

        float le = a_cur + adn;
        le = fmaxf(le, NEG * le);
        const float w = (eoff < cntc) ? __expf(le) : 0.f;
        den += w;
        wrow[lane] = w;
        const int colc = colv_cur;

#define GL(i) const u32* rp##i = hb + ((size_t)(u32)__builtin_amdgcn_readlane(colc, i) << 6); \
              const u32 v##i = rp##i[lane];
        GL(0) GL(1) GL(2) GL(3) GL(4) GL(5) GL(6) GL(7)
        GL(8) GL(9) GL(10) GL(11) GL(12) GL(13) GL(14) GL(15)
#undef GL
        __builtin_amdgcn_sched_barrier(0);

        const float a_n = as_[colv_nxt * H + head];
        __builtin_amdgcn_sched_barrier(0);

        {
            const float4 wa = *(const float4*)(wrow + wbase + 0);
            num0 = fmaf(wa.x, lo16(v0), num0);  num1 = fmaf(wa.x, hi16(v0), num1);
            num0 = fmaf(wa.y, lo16(v1), num0);  num1 = fmaf(wa.y, hi16(v1), num1);
            num0 = fmaf(wa.z, lo16(v2), num0);  num1 = fmaf(wa.z, hi16(v2), num1);
            num0 = fmaf(wa.w, lo16(v3), num0);  num1 = fmaf(wa.w, hi16(v3), num1);
            const float4 wb = *(const float4*)(wrow + wbase + 4);
            num0 = fmaf(wb.x, lo16(v4), num0);  num1 = fmaf(wb.x, hi16(v4), num1);
            num0 = fmaf(wb.y, lo16(v5), num0);  num1 = fmaf(wb.y, hi16(v5), num1);
            num0 = fmaf(wb.z, lo16(v6), num0);  num1 = fmaf(wb.z, hi16(v6), num1);
            num0 = fmaf(wb.w, lo16(v7), num0);  num1 = fmaf(wb.w, hi16(v7), num1);
            const float4 wc = *(const float4*)(wrow + wbase + 8);
            num0 = fmaf(wc.x, lo16(v8), num0);  num1 = fmaf(wc.x, hi16(v8), num1);
            num0 = fmaf(wc.y, lo16(v9), num0);  num1 = fmaf(wc.y, hi16(v9), num1);
            num0 = fmaf(wc.z, lo16(v10), num0); num1 = fmaf(wc.z, hi16(v10), num1);
            num0 = fmaf(wc.w, lo16(v11), num0); num1 = fmaf(wc.w, hi16(v11), num1);
            const float4 wd = *(const float4*)(wrow + wbase + 12);
            num0 = fmaf(wd.x, lo16(v12), num0); num1 = fmaf(wd.x, hi16(v12), num1);
            num0 = fmaf(wd.y, lo16(v13), num0); num1 = fmaf(wd.y, hi16(v13), num1);
            num0 = fmaf(wd.z, lo16(v14), num0); num1 = fmaf(wd.z, hi16(v14), num1);
            num0 = fmaf(wd.w, lo16(v15), num0); num1 = fmaf(wd.w, hi16(v15), num1);
        }

        colv_cur = colv_nxt; colv_nxt = colv_f;
        a_cur = a_n;
        cntc = cntn; cntn = cnt2;
    }

#pragma unroll
    for (int off = 1; off < 16; off <<= 1) den += __shfl_xor(den, off, 64);

    const int c0 = lane * 2;
    const float inv_den = 1.f / (den + SEPS);
    const float2 bi = *(const float2*)(bias + c0);
    float v0 = num0 * inv_den + bi.x;
    float v1 = num1 * inv_den + bi.y;

    float sum = v0 + v1;
#pragma unroll
    for (int off = 32; off; off >>= 1) sum += __shfl_xor(sum, off, 64);
    const float mu = sum * (1.0f / C);
    const float d0 = v0 - mu, d1 = v1 - mu;
    float sq = d0 * d0 + d1 * d1;
#pragma unroll
    for (int off = 32; off; off >>= 1) sq += __shfl_xor(sq, off, 64);
    const float inv = rsqrtf(sq * (1.0f / C) + LEPS);
    const float2 ga = *(const float2*)(gamma + c0);
    const float2 be = *(const float2*)(beta  + c0);
    float y0 = d0 * inv * ga.x + be.x;
    float y1 = d1 * inv * ga.y + be.y;
    y0 = y0 > 0.f ? y0 : __expf(y0) - 1.f;
    y1 = y1 > 0.f ? y1 : __expf(y1) - 1.f;
    float2 o; o.x = y0; o.y = y1;
    *(float2*)(out + (size_t)n * C + c0) = o;
}

extern "C" void kernel_launch(void* const* d_in, const int* in_sizes, int n_in,
                              void* d_out, int out_size, void* d_ws, size_t ws_size,
                              hipStream_t stream)
{
    const float* x     = (const float*)d_in[0];
    const int*   ei    = (const int*)  d_in[1];
    const float* W     = (const float*)d_in[2];
    const float* att_s = (const float*)d_in[3];
    const float* att_d = (const float*)d_in[4];
    const float* bias  = (const float*)d_in[5];
    const float* gamma = (const float*)d_in[6];
    const float* beta  = (const float*)d_in[7];
    float* out = (float*)d_out;

    // ws (~26 MB): hb bf16[N*C] | as_ | ad_ | pairs u32[NB*CAP] | col u16[E+64]
    //            | row_ptr int[N+1] | gcur u32[NB] | bbase u32[NB] | wt_hi/lo u16[128*128]
    char* p = (char*)d_ws;
    bf16*  hb      = (bf16*)p;   p += (size_t)N * C * sizeof(bf16);
    float* as_     = (float*)p;  p += (size_t)N * H * sizeof(float);
    float* ad_     = (float*)p;  p += (size_t)N * H * sizeof(float);
    u32*   pairs   = (u32*)p;    p += (size_t)NB * CAP * sizeof(u32);
    u16*   col     = (u16*)p;    p += ((size_t)(E + 64) * sizeof(u16) + 15) & ~(size_t)15;
    int*   row_ptr = (int*)p;    p += ((size_t)(N + 1) * sizeof(int) + 15) & ~(size_t)15;
    u32*   gcur    = (u32*)p;    p += (size_t)NB * sizeof(u32);
    u32*   bbase   = (u32*)p;    p += (((size_t)NB * sizeof(u32)) + 15) & ~(size_t)15;
    u16*   wt_hi   = (u16*)p;    p += (size_t)128 * 128 * sizeof(u16);
    u16*   wt_lo   = (u16*)p;

    hipMemsetAsync(gcur, 0, NB * sizeof(u32), stream);
    k0_wprep<<<64, 256, 0, stream>>>(W, wt_hi, wt_lo);
    k1_mfma<<<(N + 63) / 64, 256, 0, stream>>>(x, wt_hi, wt_lo, att_s, att_d,
                                               (u16*)hb, as_, ad_);
    kbin<<<E / CHUNK, 256, 0, stream>>>(ei, gcur, pairs);
    kscan<<<1, 64, 0, stream>>>(gcur, bbase, row_ptr);
    kfill2<<<NB, 256, 0, stream>>>(pairs, gcur, bbase, row_ptr, col);
    kd_agg_ln<<<(N * 64) / 256, 256, 0, stream>>>(
        row_ptr, col, (const u32*)hb, as_, ad_, bias, gamma, beta, out);
}

// Round 5
// 214.561 us; speedup vs baseline: 1.1434x; 1.0427x over previous
//
#include <hip/hip_runtime.h>
#include <hip/hip_bf16.h>

typedef __hip_bfloat16 bf16;
typedef unsigned int u32;
typedef unsigned short u16;
typedef __attribute__((ext_vector_type(8))) short bf16x8;
typedef __attribute__((ext_vector_type(4))) float f32x4;

constexpr int N   = 50000;
constexpr int E   = 1600000;
constexpr int C   = 128;             // channels (H * 32)
constexpr int H   = 4;               // heads
constexpr int NB  = 782;             // dst buckets of 64 nodes (782*64 >= 50000)
constexpr int CAP = 2560;            // LDS staging capacity per bucket in kfill2
constexpr int NCH = 256;             // chunks (bin-count blocks)
constexpr int CHUNK = E / NCH;       // 6250 edges per chunk (exact)
constexpr int GEMM_BLOCKS = 782;     // 782*64 >= 50000 nodes
constexpr float NEG  = 0.2f;
constexpr float SEPS = 1e-16f;
constexpr float LEPS = 1e-5f;

__device__ __forceinline__ float lo16(u32 v) { return __uint_as_float(v << 16); }
__device__ __forceinline__ float hi16(u32 v) { return __uint_as_float(v & 0xFFFF0000u); }
__device__ __forceinline__ u16 bfbits(float f) {
    __hip_bfloat16 h = __float2bfloat16(f);
    return *reinterpret_cast<u16*>(&h);
}

// F1: fused independent front-end.
//   blocks [0,782): MFMA GEMM h = x @ W (split-bf16, W converted inline from
//     f32 — k0 eliminated), fused att dots, bf16 hb store. Same numerics as R4.
//   blocks [782,1038): per-chunk dst-bucket counts -> gcnt[b][c] (no atomics
//     beyond LDS; replaces kbin phase A+B's contended global reservation).
__global__ __launch_bounds__(256) void f1_gemm_count(
    const float* __restrict__ x, const float* __restrict__ W,
    const float* __restrict__ att_s, const float* __restrict__ att_d,
    const int* __restrict__ ei,
    u16* __restrict__ hb, float* __restrict__ as_, float* __restrict__ ad_,
    u32* __restrict__ gcnt)
{
    constexpr int LDX = 136;                  // row stride in bf16 elems (128+8)
    union Smem {
        struct { u16 xhi[64 * LDX]; u16 xlo[64 * LDX]; } g;   // 34816 B
        u32 lcnt[NB];                                          // 3128 B
    };
    __shared__ Smem sm;
    const int t = threadIdx.x;

    if (blockIdx.x >= GEMM_BLOCKS) {
        // ---- bin count branch ----
        const int c = blockIdx.x - GEMM_BLOCKS;
        const int base = c * CHUNK;
        for (int i = t; i < NB; i += 256) sm.lcnt[i] = 0;
        __syncthreads();
        for (int i = t; i < CHUNK; i += 256)
            atomicAdd(&sm.lcnt[((u32)ei[E + base + i]) >> 6], 1u);
        __syncthreads();
        for (int i = t; i < NB; i += 256) gcnt[i * NCH + c] = sm.lcnt[i];
        return;
    }

    // ---- GEMM branch (R4-validated numerics) ----
    const int m0 = blockIdx.x * 64;

    // stage x tile: 64 rows x 128 f32 -> bf16 hi/lo, clamp OOB rows
#pragma unroll
    for (int it = 0; it < 8; ++it) {
        const int idx = it * 1024 + t * 4;    // element index (float granule of 4)
        const int r = idx >> 7, cc = idx & 127;
        const int gr = min(m0 + r, N - 1);
        const float4 v = *(const float4*)(x + (size_t)gr * 128 + cc);
        ushort4 sh, sl;
        {
            __hip_bfloat16 h0 = __float2bfloat16(v.x);
            __hip_bfloat16 h1 = __float2bfloat16(v.y);
            __hip_bfloat16 h2 = __float2bfloat16(v.z);
            __hip_bfloat16 h3 = __float2bfloat16(v.w);
            sh.x = *(u16*)&h0; sh.y = *(u16*)&h1; sh.z = *(u16*)&h2; sh.w = *(u16*)&h3;
            sl.x = bfbits(v.x - __bfloat162float(h0));
            sl.y = bfbits(v.y - __bfloat162float(h1));
            sl.z = bfbits(v.z - __bfloat162float(h2));
            sl.w = bfbits(v.w - __bfloat162float(h3));
        }
        *(ushort4*)(sm.g.xhi + r * LDX + cc) = sh;
        *(ushort4*)(sm.g.xlo + r * LDX + cc) = sl;
    }
    __syncthreads();

    const int lane = t & 63;
    const int w    = t >> 6;                  // wave id: rows [w*16, w*16+16)
    const int arow = w * 16 + (lane & 15);
    const int akg  = lane >> 4;               // k-group 0..3 (8 elems each)
    const int bcol = lane & 15;               // col within n-tile
    const int aq   = lane >> 4;               // C/D row quarter

    bf16x8 Ah[4], Al[4];
#pragma unroll
    for (int ks = 0; ks < 4; ++ks) {
        Ah[ks] = *(const bf16x8*)(sm.g.xhi + arow * LDX + ks * 32 + akg * 8);
        Al[ks] = *(const bf16x8*)(sm.g.xlo + arow * LDX + ks * 32 + akg * 8);
    }

    f32x4 acc[8];
#pragma unroll
    for (int nt = 0; nt < 8; ++nt) acc[nt] = f32x4{0.f, 0.f, 0.f, 0.f};

#pragma unroll
    for (int nt = 0; nt < 8; ++nt) {
        const int ch = nt * 16 + bcol;
#pragma unroll
        for (int ks = 0; ks < 4; ++ks) {
            const int kk = ks * 32 + akg * 8;
            bf16x8 Bh, Bl;
#pragma unroll
            for (int j = 0; j < 8; ++j) {
                const float wv = W[(size_t)(kk + j) * 128 + ch];
                const __hip_bfloat16 hh = __float2bfloat16(wv);
                Bh[j] = *(const short*)&hh;
                const __hip_bfloat16 hl = __float2bfloat16(wv - __bfloat162float(hh));
                Bl[j] = *(const short*)&hl;
            }
            acc[nt] = __builtin_amdgcn_mfma_f32_16x16x32_bf16(Ah[ks], Bh, acc[nt], 0, 0, 0);
            acc[nt] = __builtin_amdgcn_mfma_f32_16x16x32_bf16(Al[ks], Bh, acc[nt], 0, 0, 0);
            acc[nt] = __builtin_amdgcn_mfma_f32_16x16x32_bf16(Ah[ks], Bl, acc[nt], 0, 0, 0);
        }
    }

    // hb store: C/D layout col=lane&15, row=(lane>>4)*4+reg  [m89/m91]
#pragma unroll
    for (int nt = 0; nt < 8; ++nt) {
        const int ch = nt * 16 + bcol;
#pragma unroll
        for (int r = 0; r < 4; ++r) {
            const int node = m0 + w * 16 + aq * 4 + r;
            if (node < N) hb[(size_t)node * 128 + ch] = bfbits(acc[nt][r]);
        }
    }

    // fused attention dots: per (node, head) sum over the head's 32 channels
    float ps[4][4], pd[4][4];                 // [head][r]
#pragma unroll
    for (int h = 0; h < 4; ++h) {
        const float a0 = att_s[32 * h + bcol], a1 = att_s[32 * h + 16 + bcol];
        const float d0 = att_d[32 * h + bcol], d1 = att_d[32 * h + 16 + bcol];
#pragma unroll
        for (int r = 0; r < 4; ++r) {
            ps[h][r] = acc[2 * h][r] * a0 + acc[2 * h + 1][r] * a1;
            pd[h][r] = acc[2 * h][r] * d0 + acc[2 * h + 1][r] * d1;
        }
    }
#pragma unroll
    for (int off = 1; off < 16; off <<= 1) {
#pragma unroll
        for (int h = 0; h < 4; ++h)
#pragma unroll
            for (int r = 0; r < 4; ++r) {
                ps[h][r] += __shfl_xor(ps[h][r], off, 64);
                pd[h][r] += __shfl_xor(pd[h][r], off, 64);
            }
    }
    if (bcol == 0) {
#pragma unroll
        for (int r = 0; r < 4; ++r) {
            const int node = m0 + w * 16 + aq * 4 + r;
            if (node < N) {
#pragma unroll
                for (int h = 0; h < 4; ++h) {
                    as_[node * H + h] = ps[h][r];
                    ad_[node * H + h] = pd[h][r];
                }
            }
        }
    }
}

// S2A: block per bucket — exclusive scan of the 256 chunk-counts of bucket b.
// gbase[b][c] = sum of gcnt[b][0..c-1]; tot[b] = bucket total.
__global__ __launch_bounds__(256) void s2a_scan(
    const u32* __restrict__ gcnt, u32* __restrict__ gbase, u32* __restrict__ tot)
{
    __shared__ u32 wsum[4];
    const int b = blockIdx.x, t = threadIdx.x, lane = t & 63, w = t >> 6;
    const u32 v = gcnt[b * NCH + t];
    u32 incl = v;
#pragma unroll
    for (int off = 1; off < 64; off <<= 1) {
        u32 u = __shfl_up(incl, off, 64);
        if (lane >= off) incl += u;
    }
    if (lane == 63) wsum[w] = incl;
    __syncthreads();
    u32 wpre = 0;
#pragma unroll
    for (int i = 0; i < 4; ++i) if (i < w) wpre += wsum[i];
    gbase[b * NCH + t] = wpre + incl - v;
    if (t == 255) tot[b] = wpre + incl;
}

// KBINB: block per chunk. Redundant in-block scan of tot[] gives global bucket
// bases (no extra launch); lbase[b] = bbase[b] + gbase[b][c]. Re-read edges,
// scatter packed (src | (dst&63)<<16) into DENSE pairs[E] via LDS cursors.
// Zero global atomics.
__global__ __launch_bounds__(256) void kbinB(
    const int* __restrict__ ei, const u32* __restrict__ gbase,
    const u32* __restrict__ tot, u32* __restrict__ pairs)
{
    __shared__ u32 sl[NB];
    __shared__ u32 lfill[NB];
    __shared__ u32 wsum[4];
    const int t = threadIdx.x, lane = t & 63, w = t >> 6;
    const int c = blockIdx.x;

    u32 carry = 0;
    for (int q = 0; q < 4; ++q) {
        const int idx = q * 256 + t;
        const u32 v = (idx < NB) ? tot[idx] : 0u;
        u32 incl = v;
#pragma unroll
        for (int off = 1; off < 64; off <<= 1) {
            u32 u = __shfl_up(incl, off, 64);
            if (lane >= off) incl += u;
        }
        if (lane == 63) wsum[w] = incl;
        __syncthreads();
        u32 wpre = 0, wtot = 0;
#pragma unroll
        for (int i = 0; i < 4; ++i) { const u32 s = wsum[i]; wtot += s; if (i < w) wpre += s; }
        if (idx < NB) sl[idx] = carry + wpre + (incl - v) + gbase[(size_t)idx * NCH + c];
        carry += wtot;
        __syncthreads();
    }
    for (int i = t; i < NB; i += 256) lfill[i] = 0u;
    __syncthreads();

    const int base = c * CHUNK;
    for (int i = t; i < CHUNK; i += 256) {
        const u32 src = (u32)ei[base + i];
        const u32 dst = (u32)ei[E + base + i];
        const u32 b = dst >> 6;
        const u32 pos = atomicAdd(&lfill[b], 1u);
        pairs[sl[b] + pos] = src | ((dst & 63u) << 16);
    }
}

// KFILL2: block per bucket. base = sum(tot[0..b-1]) via in-block reduce.
// Pairs staged once in LDS; per-node count + scan + scatter in LDS; col
// written back coalesced. Writes row_ptr; block 0 writes row_ptr[N]=E.
__global__ __launch_bounds__(256) void kfill2(
    const u32* __restrict__ pairs, const u32* __restrict__ tot,
    int* __restrict__ row_ptr, u16* __restrict__ col)
{
    __shared__ u32 spr[CAP];
    __shared__ u16 scol[CAP];
    __shared__ int jcnt[64], joff[64], jcur[64];
    __shared__ u32 rsum[4];
    const int b = blockIdx.x, t = threadIdx.x;
    const int lane = t & 63, w = t >> 6;

    u32 part = 0;
    for (int i = t; i < b; i += 256) part += tot[i];
#pragma unroll
    for (int off = 32; off; off >>= 1) part += __shfl_xor(part, off, 64);
    if (lane == 0) rsum[w] = part;
    if (t < 64) jcnt[t] = 0;
    __syncthreads();
    const int base = (int)(rsum[0] + rsum[1] + rsum[2] + rsum[3]);
    const int cntb = (int)tot[b];

    const u32* pr = pairs + base;
    for (int i = t; i < cntb; i += 256) spr[i] = pr[i];
    __syncthreads();
    for (int i = t; i < cntb; i += 256) atomicAdd(&jcnt[spr[i] >> 16], 1);
    __syncthreads();
    if (t < 64) {
        int v = jcnt[t], incl = v;
#pragma unroll
        for (int off = 1; off < 64; off <<= 1) {
            int u = __shfl_up(incl, off, 64);
            if (t >= off) incl += u;
        }
        joff[t] = incl - v;
        const int n = b * 64 + t;
        if (n < N) row_ptr[n] = base + joff[t];
        jcur[t] = 0;
    }
    __syncthreads();
    for (int i = t; i < cntb; i += 256) {
        const u32 p = spr[i];
        const int j = p >> 16;
        const int pos = atomicAdd(&jcur[j], 1);
        scol[joff[j] + pos] = (u16)(p & 0xFFFFu);
    }
    __syncthreads();
    for (int i = t; i < cntb; i += 256) col[base + i] = scol[i];
    if (b == 0 && t == 0) row_ptr[N] = E;
}

// KD v4 (byte-identical to R3/R4 — control).
__global__ __launch_bounds__(256) void kd_agg_ln(
    const int* __restrict__ row_ptr, const u16* __restrict__ col,
    const u32* __restrict__ hb, const float* __restrict__ as_,
    const float* __restrict__ ad_,
    const float* __restrict__ bias, const float* __restrict__ gamma,
    const float* __restrict__ beta, float* __restrict__ out)
{
    __shared__ float wlds[4][64];
    const int tid  = threadIdx.x;
    const int lane = tid & 63;
    const int wv   = __builtin_amdgcn_readfirstlane(tid >> 6);
    const int n    = __builtin_amdgcn_readfirstlane((int)blockIdx.x * 4 + (tid >> 6));
    if (n >= N) return;

    const int head  = lane >> 4;
    const int eoff  = lane & 15;
    const int wbase = head << 4;
    float* __restrict__ wrow = wlds[wv];

    const float adn = ad_[n * H + head];
    const float asn = as_[n * H + head];

    float ls = asn + adn;
    ls = fmaxf(ls, NEG * ls);
    const float wself = __expf(ls);
    float den = (eoff == 0) ? wself : 0.f;
    const u32 hvs = hb[n * 64 + lane];
    float num0 = wself * lo16(hvs);
    float num1 = wself * hi16(hvs);

    const int k0  = row_ptr[n];
    const int deg = row_ptr[n + 1] - k0;
    const int ntiles = (deg + 15) >> 4;

    const int cnt0 = deg < 16 ? deg : 16;
    const int cnt1 = (deg - 16) < 16 ? (deg - 16) : 16;
    int colv_cur = (eoff < cnt0) ? (int)col[k0 + eoff]      : 0;
    int colv_nxt = (eoff < cnt1) ? (int)col[k0 + 16 + eoff] : 0;
    float a_cur  = as_[colv_cur * H + head];
    int cntc = cnt0, cntn = cnt1;

    int k = k0;
    for (int t = 0; t < ntiles; ++t, k += 16) {
        const int rem2 = deg - 16 * (t + 2);
        const int cnt2 = rem2 < 16 ? rem2 : 16;
        const int cf_raw = (int)col[k + 32 + eoff];
        const int colv_f = (eoff < cnt2) ? cf_raw : 0;

        float le = a_cur + adn;
        le = fmaxf(le, NEG * le);
        const float w = (eoff < cntc) ? __expf(le) : 0.f;
        den += w;
        wrow[lane] = w;
        const int colc = colv_cur;

#define GL(i) const u32* rp##i = hb + ((size_t)(u32)__builtin_amdgcn_readlane(colc, i) << 6); \
              const u32 v##i = rp##i[lane];
        GL(0) GL(1) GL(2) GL(3) GL(4) GL(5) GL(6) GL(7)
        GL(8) GL(9) GL(10) GL(11) GL(12) GL(13) GL(14) GL(15)
#undef GL
        __builtin_amdgcn_sched_barrier(0);

        const float a_n = as_[colv_nxt * H + head];
        __builtin_amdgcn_sched_barrier(0);

        {
            const float4 wa = *(const float4*)(wrow + wbase + 0);
            num0 = fmaf(wa.x, lo16(v0), num0);  num1 = fmaf(wa.x, hi16(v0), num1);
            num0 = fmaf(wa.y, lo16(v1), num0);  num1 = fmaf(wa.y, hi16(v1), num1);
            num0 = fmaf(wa.z, lo16(v2), num0);  num1 = fmaf(wa.z, hi16(v2), num1);
            num0 = fmaf(wa.w, lo16(v3), num0);  num1 = fmaf(wa.w, hi16(v3), num1);
            const float4 wb = *(const float4*)(wrow + wbase + 4);
            num0 = fmaf(wb.x, lo16(v4), num0);  num1 = fmaf(wb.x, hi16(v4), num1);
            num0 = fmaf(wb.y, lo16(v5), num0);  num1 = fmaf(wb.y, hi16(v5), num1);
            num0 = fmaf(wb.z, lo16(v6), num0);  num1 = fmaf(wb.z, hi16(v6), num1);
            num0 = fmaf(wb.w, lo16(v7), num0);  num1 = fmaf(wb.w, hi16(v7), num1);
            const float4 wc = *(const float4*)(wrow + wbase + 8);
            num0 = fmaf(wc.x, lo16(v8), num0);  num1 = fmaf(wc.x, hi16(v8), num1);
            num0 = fmaf(wc.y, lo16(v9), num0);  num1 = fmaf(wc.y, hi16(v9), num1);
            num0 = fmaf(wc.z, lo16(v10), num0); num1 = fmaf(wc.z, hi16(v10), num1);
            num0 = fmaf(wc.w, lo16(v11), num0); num1 = fmaf(wc.w, hi16(v11), num1);
            const float4 wd = *(const float4*)(wrow + wbase + 12);
            num0 = fmaf(wd.x, lo16(v12), num0); num1 = fmaf(wd.x, hi16(v12), num1);
            num0 = fmaf(wd.y, lo16(v13), num0); num1 = fmaf(wd.y, hi16(v13), num1);
            num0 = fmaf(wd.z, lo16(v14), num0); num1 = fmaf(wd.z, hi16(v14), num1);
            num0 = fmaf(wd.w, lo16(v15), num0); num1 = fmaf(wd.w, hi16(v15), num1);
        }

        colv_cur = colv_nxt; colv_nxt = colv_f;
        a_cur = a_n;
        cntc = cntn; cntn = cnt2;
    }

#pragma unroll
    for (int off = 1; off < 16; off <<= 1) den += __shfl_xor(den, off, 64);

    const int c0 = lane * 2;
    const float inv_den = 1.f / (den + SEPS);
    const float2 bi = *(const float2*)(bias + c0);
    float v0 = num0 * inv_den + bi.x;
    float v1 = num1 * inv_den + bi.y;

    float sum = v0 + v1;
#pragma unroll
    for (int off = 32; off; off >>= 1) sum += __shfl_xor(sum, off, 64);
    const float mu = sum * (1.0f / C);
    const float d0 = v0 - mu, d1 = v1 - mu;
    float sq = d0 * d0 + d1 * d1;
#pragma unroll
    for (int off = 32; off; off >>= 1) sq += __shfl_xor(sq, off, 64);
    const float inv = rsqrtf(sq * (1.0f / C) + LEPS);
    const float2 ga = *(const float2*)(gamma + c0);
    const float2 be = *(const float2*)(beta  + c0);
    float y0 = d0 * inv * ga.x + be.x;
    float y1 = d1 * inv * ga.y + be.y;
    y0 = y0 > 0.f ? y0 : __expf(y0) - 1.f;
    y1 = y1 > 0.f ? y1 : __expf(y1) - 1.f;
    float2 o; o.x = y0; o.y = y1;
    *(float2*)(out + (size_t)n * C + c0) = o;
}

extern "C" void kernel_launch(void* const* d_in, const int* in_sizes, int n_in,
                              void* d_out, int out_size, void* d_ws, size_t ws_size,
                              hipStream_t stream)
{
    const float* x     = (const float*)d_in[0];
    const int*   ei    = (const int*)  d_in[1];
    const float* W     = (const float*)d_in[2];
    const float* att_s = (const float*)d_in[3];
    const float* att_d = (const float*)d_in[4];
    const float* bias  = (const float*)d_in[5];
    const float* gamma = (const float*)d_in[6];
    const float* beta  = (const float*)d_in[7];
    float* out = (float*)d_out;

    // ws (~25.8 MB): hb bf16[N*C] | as_ | ad_ | pairs u32[E] | col u16[E+64]
    //              | row_ptr int[N+1] | gcnt u32[NB*256] | gbase u32[NB*256] | tot u32[NB]
    char* p = (char*)d_ws;
    bf16*  hb      = (bf16*)p;   p += (size_t)N * C * sizeof(bf16);
    float* as_     = (float*)p;  p += (size_t)N * H * sizeof(float);
    float* ad_     = (float*)p;  p += (size_t)N * H * sizeof(float);
    u32*   pairs   = (u32*)p;    p += (size_t)E * sizeof(u32);
    u16*   col     = (u16*)p;    p += ((size_t)(E + 64) * sizeof(u16) + 15) & ~(size_t)15;
    int*   row_ptr = (int*)p;    p += ((size_t)(N + 1) * sizeof(int) + 15) & ~(size_t)15;
    u32*   gcnt    = (u32*)p;    p += (size_t)NB * NCH * sizeof(u32);
    u32*   gbase   = (u32*)p;    p += (size_t)NB * NCH * sizeof(u32);
    u32*   tot     = (u32*)p;

    f1_gemm_count<<<GEMM_BLOCKS + NCH, 256, 0, stream>>>(
        x, W, att_s, att_d, ei, (u16*)hb, as_, ad_, gcnt);
    s2a_scan<<<NB, 256, 0, stream>>>(gcnt, gbase, tot);
    kbinB<<<NCH, 256, 0, stream>>>(ei, gbase, tot, pairs);
    kfill2<<<NB, 256, 0, stream>>>(pairs, tot, row_ptr, col);
    kd_agg_ln<<<(N * 64) / 256, 256, 0, stream>>>(
        row_ptr, col, (const u32*)hb, as_, ad_, bias, gamma, beta, out);
}